// Round 9
// baseline (489.674 us; speedup 1.0000x reference)
//
#include <hip/hip_runtime.h>

// Problem constants
#define NITEMS 50000
#define EMBD   16
#define NSLATE 10
#define HIDD   512
#define LATD   64
#define RESPD  1024
#define BATCH  256
#define NCHUNK 8
#define CHUNK  6250   // score: NITEMS/8
#define PCHUNK 3125   // pool: NITEMS/16
#define LOG2E  1.44269504088896340736f
#define SHIFT  64.0f  // fixed log2-domain shift: s = sum exp2(x*log2e - 64)

// d_out layout (float): z_mean | z_log_var | recon_slate | recon_resp
#define OUT_ZM 0
#define OUT_ZLV 16384
#define OUT_RS 32768
#define OUT_RR 35328

// ws layout (floats), time-overlays (stream-ordered), round-6 proven footprint:
//   [0 .. 307200)        x (build -> enc)     OVERLAY p2[8*40960=327680] (d2 -> d2-finish)
//   [307200 .. 589824)   dz (build/mulv -> d1)
//   [589824 .. 868352)   pp (pool partials)
//   [589824 .. 1114112)  OVERLAY part[4*131072] (enc->mulv, d1->d2)
//   [1114112 .. 1155072) rx[40960] (d2-finish -> score; pre-scaled by LOG2E)
//   [1155072 .. 1216512) sps/spm/spa
//   [1216512 .. 1217036) counters (zeroed by hipMemsetAsync each launch)
#define WS_X      0
#define WS_P2     0
#define WS_DZ     307200
#define WS_PP     589824
#define WS_PART   589824
#define WS_RX     1114112
#define WS_SPS    1155072
#define WS_SPM    1175552
#define WS_SPA    1196032
#define WS_CNT    1216512   // cnt_pool[256] | cnt_d2[12] | cnt_score[256]
#define CNT_POOL  0
#define CNT_D2    256
#define CNT_SCORE 268
#define CNT_INTS  524

// Pool partials + fused build_x: grid (256 b, 16 c). Per-wave 17-float partial -> pp;
// the last block of each row b (atomic counter) builds x/dz for that row.
__global__ __launch_bounds__(256) void pool_build(const int* __restrict__ u,
    const int* __restrict__ slate, const float* __restrict__ resp,
    const float* __restrict__ emb, float* __restrict__ pp,
    float* __restrict__ x, float* __restrict__ dz, int* __restrict__ cnt) {
  __shared__ float fin[17];
  __shared__ int flag;
  int b = blockIdx.x, c = blockIdx.y, t = threadIdx.x;
  float acc[16];
  #pragma unroll
  for (int i = 0; i < 16; ++i) acc[i] = 0.0f;
  float cn = 0.0f;
  const int* ub = u + (size_t)b * NITEMS;
  int n1 = c * PCHUNK + PCHUNK;
  for (int n = c * PCHUNK + t; n < n1; n += 256) {
    if (ub[n]) {
      const float4* e4 = (const float4*)(emb + (size_t)n * 16);
      float4 a = e4[0], bb = e4[1], cc = e4[2], dd = e4[3];
      acc[0] += a.x;  acc[1] += a.y;  acc[2] += a.z;  acc[3] += a.w;
      acc[4] += bb.x; acc[5] += bb.y; acc[6] += bb.z; acc[7] += bb.w;
      acc[8] += cc.x; acc[9] += cc.y; acc[10] += cc.z; acc[11] += cc.w;
      acc[12] += dd.x; acc[13] += dd.y; acc[14] += dd.z; acc[15] += dd.w;
      cn += 1.0f;
    }
  }
  #pragma unroll
  for (int off = 32; off > 0; off >>= 1) {
    #pragma unroll
    for (int i = 0; i < 16; ++i) acc[i] += __shfl_down(acc[i], off);
    cn += __shfl_down(cn, off);
  }
  int lane = t & 63, wv = t >> 6;
  if (lane == 0) {
    float* dst = pp + ((size_t)(b * 16 + c) * 4 + wv) * 17;
    #pragma unroll
    for (int i = 0; i < 16; ++i) dst[i] = acc[i];
    dst[16] = cn;
  }
  __syncthreads();
  if (t == 0) {
    __threadfence();
    int old = atomicAdd(cnt + CNT_POOL + b, 1);
    flag = (old == 15);
  }
  __syncthreads();
  if (flag) {
    // last block for row b: build x = [slate(160)|user(16)|resp(1024)], dz[64:1104]
    if (t < 17) {
      __threadfence();
      float a = 0.f;
      const float* p = pp + (size_t)b * 64 * 17 + t;
      #pragma unroll
      for (int w = 0; w < 64; ++w) a += p[w * 17];
      fin[t] = a;
    }
    __syncthreads();
    float inv = 1.0f / fin[16];
    if (t < 16) {
      float uv = fin[t] * inv;
      x[b * 1200 + 160 + t] = uv;
      dz[b * 1104 + 64 + t] = uv;
    }
    if (t >= 32 && t < 192) {
      int i = t - 32;
      int k = i >> 4, e = i & 15;
      int it = slate[b * 10 + k];
      x[b * 1200 + i] = emb[(size_t)it * 16 + e];
    }
    for (int i = t; i < 1024; i += 256) {
      float r = resp[b * 1024 + i];
      x[b * 1200 + 176 + i] = r;
      dz[b * 1104 + 80 + i] = r;
    }
  }
}

// Split-K partial GEMM: P[z][M,N] = A[M,ks:ke] @ B[N,ks:ke]^T (round-6 proven)
__global__ __launch_bounds__(256) void gemm64(const float* __restrict__ A,
    const float* __restrict__ B, float* __restrict__ P, int M, int N, int K, int kChunk) {
  __shared__ float As[16][68];
  __shared__ float Bs[16][68];
  int tid = threadIdx.x;
  int m0 = blockIdx.y * 64, n0 = blockIdx.x * 64;
  int ks = blockIdx.z * kChunk;
  int ke = ks + kChunk; if (ke > K) ke = K;
  int sr = tid >> 2, sc = (tid & 3) * 4;
  int tx = tid & 15, ty = tid >> 4;
  float acc[4][4];
  #pragma unroll
  for (int i = 0; i < 4; ++i)
    #pragma unroll
    for (int j = 0; j < 4; ++j) acc[i][j] = 0.f;
  for (int k0 = ks; k0 < ke; k0 += 16) {
    float4 av = make_float4(0.f, 0.f, 0.f, 0.f);
    float4 bv = make_float4(0.f, 0.f, 0.f, 0.f);
    if (k0 + sc < ke)
      av = *(const float4*)(A + (size_t)(m0 + sr) * K + k0 + sc);
    if (k0 + sc < ke && n0 + sr < N)
      bv = *(const float4*)(B + (size_t)(n0 + sr) * K + k0 + sc);
    __syncthreads();
    As[sc][sr] = av.x; As[sc + 1][sr] = av.y; As[sc + 2][sr] = av.z; As[sc + 3][sr] = av.w;
    Bs[sc][sr] = bv.x; Bs[sc + 1][sr] = bv.y; Bs[sc + 2][sr] = bv.z; Bs[sc + 3][sr] = bv.w;
    __syncthreads();
    #pragma unroll
    for (int kk = 0; kk < 16; ++kk) {
      float4 a4 = *(const float4*)&As[kk][4 * ty];
      float4 b4 = *(const float4*)&Bs[kk][4 * tx];
      float a[4] = {a4.x, a4.y, a4.z, a4.w};
      float b[4] = {b4.x, b4.y, b4.z, b4.w};
      #pragma unroll
      for (int i = 0; i < 4; ++i)
        #pragma unroll
        for (int j = 0; j < 4; ++j) acc[i][j] = fmaf(a[i], b[j], acc[i][j]);
    }
  }
  float* Pz = P + (size_t)blockIdx.z * M * N;
  #pragma unroll
  for (int i = 0; i < 4; ++i) {
    int m = m0 + 4 * ty + i, n = n0 + 4 * tx;
    if (n < N)
      *(float4*)(Pz + (size_t)m * N + n) = make_float4(acc[i][0], acc[i][1], acc[i][2], acc[i][3]);
  }
}

// h = relu(sum_s part[s] + b_enc); z_mean/z_log_var -> out; z -> dz[0:64]
__global__ __launch_bounds__(128) void mulv_z_kernel(const float* __restrict__ part,
    const float* __restrict__ benc,
    const float* __restrict__ Wmu, const float* __restrict__ bmu,
    const float* __restrict__ Wlv, const float* __restrict__ blv,
    const float* __restrict__ eps, float* __restrict__ out, float* __restrict__ dz) {
  __shared__ __align__(16) float hs[512];
  __shared__ float zms[64], zlvs[64];
  int b = blockIdx.x, t = threadIdx.x;
  for (int i = t; i < 512; i += 128) {
    float a = benc[i];
    #pragma unroll
    for (int s = 0; s < 4; ++s) a += part[(size_t)s * 131072 + b * 512 + i];
    hs[i] = fmaxf(a, 0.f);
  }
  __syncthreads();
  const float* Wr = (t < 64) ? (Wmu + (size_t)t * 512) : (Wlv + (size_t)(t - 64) * 512);
  float bias = (t < 64) ? bmu[t] : blv[t - 64];
  const float4* w4 = (const float4*)Wr;
  const float4* h4 = (const float4*)hs;
  float a0 = 0.f, a1 = 0.f, a2 = 0.f, a3 = 0.f;
  #pragma unroll 4
  for (int i = 0; i < 128; ++i) {
    float4 w = w4[i], hv = h4[i];
    a0 = fmaf(w.x, hv.x, a0); a1 = fmaf(w.y, hv.y, a1);
    a2 = fmaf(w.z, hv.z, a2); a3 = fmaf(w.w, hv.w, a3);
  }
  float acc = (a0 + a1) + (a2 + a3) + bias;
  if (t < 64) { out[OUT_ZM + b * 64 + t] = acc; zms[t] = acc; }
  else        { out[OUT_ZLV + b * 64 + (t - 64)] = acc; zlvs[t - 64] = acc; }
  __syncthreads();
  if (t < 64) {
    float zv = fmaf(eps[b * 64 + t], __builtin_amdgcn_exp2f(0.7213475204444817f * zlvs[t]), zms[t]);
    dz[b * 1104 + t] = zv;
  }
}

// d2 split-K GEMM with reduce-on-load A (round-6 config, grid (3,4,8), kChunk=64)
// + fused rx finish: per-(m,n)-tile counter; last z-block finishes its tile of
// rx = relu(sum_z p2 + b_d2) * LOG2E.
__global__ __launch_bounds__(256) void gemm_d2f(const float* __restrict__ part,
    const float* __restrict__ bd1, const float* __restrict__ W,
    const float* __restrict__ bd2, float* __restrict__ p2, float* __restrict__ rx,
    int* __restrict__ cnt) {
  __shared__ float As[16][68];
  __shared__ float Bs[16][68];
  __shared__ int flag;
  const int N = 160;
  int tid = threadIdx.x;
  int m0 = blockIdx.y * 64, n0 = blockIdx.x * 64;
  int ks = blockIdx.z * 64, ke = ks + 64;
  int sr = tid >> 2, sc = (tid & 3) * 4;
  int tx = tid & 15, ty = tid >> 4;
  float acc[4][4];
  #pragma unroll
  for (int i = 0; i < 4; ++i)
    #pragma unroll
    for (int j = 0; j < 4; ++j) acc[i][j] = 0.f;
  for (int k0 = ks; k0 < ke; k0 += 16) {
    int col = k0 + sc;
    const float* p = part + (size_t)(m0 + sr) * 512 + col;
    float4 a0 = *(const float4*)(p);
    float4 a1 = *(const float4*)(p + 131072);
    float4 a2 = *(const float4*)(p + 262144);
    float4 a3 = *(const float4*)(p + 393216);
    float4 bb = *(const float4*)(bd1 + col);
    float4 av;
    av.x = fmaxf(a0.x + a1.x + a2.x + a3.x + bb.x, 0.f);
    av.y = fmaxf(a0.y + a1.y + a2.y + a3.y + bb.y, 0.f);
    av.z = fmaxf(a0.z + a1.z + a2.z + a3.z + bb.z, 0.f);
    av.w = fmaxf(a0.w + a1.w + a2.w + a3.w + bb.w, 0.f);
    float4 bv = make_float4(0.f, 0.f, 0.f, 0.f);
    if (n0 + sr < N)
      bv = *(const float4*)(W + (size_t)(n0 + sr) * 512 + col);
    __syncthreads();
    As[sc][sr] = av.x; As[sc + 1][sr] = av.y; As[sc + 2][sr] = av.z; As[sc + 3][sr] = av.w;
    Bs[sc][sr] = bv.x; Bs[sc + 1][sr] = bv.y; Bs[sc + 2][sr] = bv.z; Bs[sc + 3][sr] = bv.w;
    __syncthreads();
    #pragma unroll
    for (int kk = 0; kk < 16; ++kk) {
      float4 a4 = *(const float4*)&As[kk][4 * ty];
      float4 b4 = *(const float4*)&Bs[kk][4 * tx];
      float a[4] = {a4.x, a4.y, a4.z, a4.w};
      float b[4] = {b4.x, b4.y, b4.z, b4.w};
      #pragma unroll
      for (int i = 0; i < 4; ++i)
        #pragma unroll
        for (int j = 0; j < 4; ++j) acc[i][j] = fmaf(a[i], b[j], acc[i][j]);
    }
  }
  float* Pz = p2 + (size_t)blockIdx.z * 40960;
  #pragma unroll
  for (int i = 0; i < 4; ++i) {
    int m = m0 + 4 * ty + i, n = n0 + 4 * tx;
    if (n < N)
      *(float4*)(Pz + (size_t)m * 160 + n) = make_float4(acc[i][0], acc[i][1], acc[i][2], acc[i][3]);
  }
  __syncthreads();
  int tile = blockIdx.y * 3 + blockIdx.x;
  if (tid == 0) {
    __threadfence();
    int old = atomicAdd(cnt + CNT_D2 + tile, 1);
    flag = (old == 7);
  }
  __syncthreads();
  if (flag) {
    __threadfence();
    if (n0 + 64 <= N) {
      for (int idx = tid; idx < 4096; idx += 256) {
        int m = m0 + (idx >> 6), n = n0 + (idx & 63);
        float a = bd2[n];
        #pragma unroll
        for (int z = 0; z < 8; ++z) a += p2[(size_t)z * 40960 + m * 160 + n];
        rx[m * 160 + n] = fmaxf(a, 0.f) * LOG2E;
      }
    } else {
      for (int idx = tid; idx < 2048; idx += 256) {
        int m = m0 + (idx >> 5), n = n0 + (idx & 31);
        float a = bd2[n];
        #pragma unroll
        for (int z = 0; z < 8; ++z) a += p2[(size_t)z * 40960 + m * 160 + n];
        rx[m * 160 + n] = fmaxf(a, 0.f) * LOG2E;
      }
    }
  }
}

// Per (b, chunk): fixed-shift softmax partials; rx (global, finished, LOG2E-scaled).
// Round-7 measured config: compiler holds rx via SGPR reloads (VGPR=40, occ 47%,
// VALU 80%). DO NOT add an LDS copy of rx (rounds 2/3/6: LDS remat) and DO NOT
// raise min-waves to 3 (round 4: 620 MB scratch spill). Fused final combine:
// per-row counter, 8th block combines chunks + slate prob (replaces score_final).
__global__ __launch_bounds__(256, 2) void score_part(const float* __restrict__ rx,
    const float* __restrict__ emb, const int* __restrict__ slate,
    float* __restrict__ psg, float* __restrict__ pmg, int* __restrict__ pag,
    float* __restrict__ out, int* __restrict__ cnt) {
  __shared__ float wm[4][10], wsum[4][10];
  __shared__ int wa[4][10];
  __shared__ int flag;
  int b = blockIdx.x, c = blockIdx.y, t = threadIdx.x;
  float4 r[10][4];
  {
    const float4* rp = (const float4*)(rx + b * 160);
    #pragma unroll
    for (int k = 0; k < 10; ++k) {
      #pragma unroll
      for (int j = 0; j < 4; ++j) r[k][j] = rp[k * 4 + j];
    }
  }
  float m[10], s[10];
  int am[10];
  #pragma unroll
  for (int k = 0; k < 10; ++k) { m[k] = -3.402823466e38f; s[k] = 0.f; am[k] = 0; }
  int nBase = c * CHUNK, nEnd = nBase + CHUNK;
  const float4* ep = (const float4*)emb;
  int n = nBase + t;
  float4 e0, e1, e2, e3;
  {
    const float4* p = ep + (size_t)n * 4;
    e0 = p[0]; e1 = p[1]; e2 = p[2]; e3 = p[3];
  }
  #pragma unroll 1
  for (; n < nEnd; n += 256) {
    int nn = n + 256; if (nn > NITEMS - 1) nn = NITEMS - 1;
    const float4* p = ep + (size_t)nn * 4;
    float4 f0 = p[0], f1 = p[1], f2 = p[2], f3 = p[3];
    #pragma unroll
    for (int k = 0; k < 10; ++k) {
      float x0 = fmaf(e0.x, r[k][0].x, -SHIFT);
      float x1 = e1.x * r[k][1].x;
      float x2 = e2.x * r[k][2].x;
      float x3 = e3.x * r[k][3].x;
      x0 = fmaf(e0.y, r[k][0].y, x0);
      x1 = fmaf(e1.y, r[k][1].y, x1);
      x2 = fmaf(e2.y, r[k][2].y, x2);
      x3 = fmaf(e3.y, r[k][3].y, x3);
      x0 = fmaf(e0.z, r[k][0].z, x0);
      x1 = fmaf(e1.z, r[k][1].z, x1);
      x2 = fmaf(e2.z, r[k][2].z, x2);
      x3 = fmaf(e3.z, r[k][3].z, x3);
      x0 = fmaf(e0.w, r[k][0].w, x0);
      x1 = fmaf(e1.w, r[k][1].w, x1);
      x2 = fmaf(e2.w, r[k][2].w, x2);
      x3 = fmaf(e3.w, r[k][3].w, x3);
      float x = (x0 + x1) + (x2 + x3);
      s[k] += __builtin_amdgcn_exp2f(x);
      if (x > m[k]) { m[k] = x; am[k] = n; }
    }
    e0 = f0; e1 = f1; e2 = f2; e3 = f3;
  }
  #pragma unroll
  for (int off = 32; off > 0; off >>= 1) {
    #pragma unroll
    for (int k = 0; k < 10; ++k) {
      s[k] += __shfl_down(s[k], off);
      float om = __shfl_down(m[k], off);
      int oa = __shfl_down(am[k], off);
      bool take = (om > m[k]) || (om == m[k] && oa < am[k]);
      am[k] = take ? oa : am[k];
      m[k] = fmaxf(m[k], om);
    }
  }
  int lane = t & 63, wv = t >> 6;
  if (lane == 0) {
    #pragma unroll
    for (int k = 0; k < 10; ++k) { wm[wv][k] = m[k]; wsum[wv][k] = s[k]; wa[wv][k] = am[k]; }
  }
  __syncthreads();
  if (t < 10) {
    int k = t;
    float M = wm[0][k], S = wsum[0][k];
    int AM = wa[0][k];
    #pragma unroll
    for (int w = 1; w < 4; ++w) {
      float m2 = wm[w][k];
      int oa = wa[w][k];
      bool take = (m2 > M) || (m2 == M && oa < AM);
      AM = take ? oa : AM;
      M = fmaxf(M, m2);
      S += wsum[w][k];
    }
    int idx = (b * NCHUNK + c) * 10 + k;
    psg[idx] = S; pmg[idx] = M; pag[idx] = AM;
  }
  __syncthreads();
  if (t == 0) {
    __threadfence();
    int old = atomicAdd(cnt + CNT_SCORE + b, 1);
    flag = (old == NCHUNK - 1);
  }
  __syncthreads();
  if (flag) {
    if (t < 10) {
      __threadfence();
      int k = t;
      int base = b * NCHUNK * 10 + k;
      float S = 0.f, M = -3.402823466e38f;
      int AM = 2147483647;
      #pragma unroll
      for (int c2 = 0; c2 < NCHUNK; ++c2) {
        S += psg[base + c2 * 10];
        float m2 = pmg[base + c2 * 10];
        int oa = pag[base + c2 * 10];
        bool take = (m2 > M) || (m2 == M && oa < AM);
        AM = take ? oa : AM;
        M = fmaxf(M, m2);
      }
      int it = slate[b * 10 + k];
      const float* er = emb + (size_t)it * 16;
      const float* rr = rx + b * 160 + k * 16;
      float xs = -SHIFT;
      #pragma unroll
      for (int e = 0; e < 16; ++e) xs = fmaf(rr[e], er[e], xs);
      out[OUT_RS + b * 10 + k] = (float)AM;
      out[OUT_RR + b * 10 + k] = __builtin_amdgcn_exp2f(xs) / S;
    }
  }
}

extern "C" void kernel_launch(void* const* d_in, const int* in_sizes, int n_in,
                              void* d_out, int out_size, void* d_ws, size_t ws_size,
                              hipStream_t stream) {
  const int* user_repr = (const int*)d_in[0];
  const int* slate = (const int*)d_in[1];
  const float* resp = (const float*)d_in[2];
  const float* eps = (const float*)d_in[3];
  const float* emb = (const float*)d_in[4];
  const float* W_enc = (const float*)d_in[5];
  const float* b_enc = (const float*)d_in[6];
  const float* W_mu = (const float*)d_in[7];
  const float* b_mu = (const float*)d_in[8];
  const float* W_lv = (const float*)d_in[9];
  const float* b_lv = (const float*)d_in[10];
  const float* W_d1 = (const float*)d_in[11];
  const float* b_d1 = (const float*)d_in[12];
  const float* W_d2 = (const float*)d_in[13];
  const float* b_d2 = (const float*)d_in[14];
  float* out = (float*)d_out;
  float* ws = (float*)d_ws;

  float* x    = ws + WS_X;
  float* dz   = ws + WS_DZ;
  float* pp   = ws + WS_PP;
  float* part = ws + WS_PART;
  float* p2   = ws + WS_P2;
  float* rx   = ws + WS_RX;
  float* sps  = ws + WS_SPS;
  float* spm  = ws + WS_SPM;
  int*   spa  = (int*)(ws + WS_SPA);
  int*   cnt  = (int*)(ws + WS_CNT);

  hipMemsetAsync(cnt, 0, CNT_INTS * sizeof(int), stream);
  pool_build<<<dim3(256, 16), 256, 0, stream>>>(user_repr, slate, resp, emb, pp, x, dz, cnt);
  gemm64<<<dim3(8, 4, 4), 256, 0, stream>>>(x, W_enc, part, 256, 512, 1200, 300);
  mulv_z_kernel<<<256, 128, 0, stream>>>(part, b_enc, W_mu, b_mu, W_lv, b_lv, eps, out, dz);
  gemm64<<<dim3(8, 4, 4), 256, 0, stream>>>(dz, W_d1, part, 256, 512, 1104, 276);
  gemm_d2f<<<dim3(3, 4, 8), 256, 0, stream>>>(part, b_d1, W_d2, b_d2, p2, rx, cnt);
  score_part<<<dim3(256, 8), 256, 0, stream>>>(rx, emb, slate, sps, spm, spa, out, cnt);
}

// Round 10
// 364.745 us; speedup vs baseline: 1.3425x; 1.3425x over previous
//
#include <hip/hip_runtime.h>

// Problem constants
#define NITEMS 50000
#define EMBD   16
#define NSLATE 10
#define HIDD   512
#define LATD   64
#define RESPD  1024
#define BATCH  256
#define NCHUNK 8
#define CHUNK  6250   // score: NITEMS/8
#define PCHUNK 3125   // pool: NITEMS/16; 3125 = 12*256 + 53
#define PB     4      // batch rows per pool block
#define LOG2E  1.44269504088896340736f
#define SHIFT  64.0f  // fixed log2-domain shift: s = sum exp2(x*log2e - 64)

// d_out layout (float): z_mean | z_log_var | recon_slate | recon_resp
#define OUT_ZM 0
#define OUT_ZLV 16384
#define OUT_RS 32768
#define OUT_RR 35328

// ws layout (floats), time-overlays (stream-ordered), round-6 proven footprint:
//   [0 .. 307200)        x (build -> enc)     OVERLAY p2[8*40960] (d2 -> score)
//   [307200 .. 589824)   dz (build/mulv -> d1)
//   [589824 .. 868352)   pp (pool partials, pool -> build_x)
//   [589824 .. 1114112)  OVERLAY part[4*131072] (enc->mulv, d1->d2)
//   [1114112 .. 1155072) rx[40960]
//   [1155072 .. 1216512) sps/spm/spa
#define WS_X    0
#define WS_P2   0
#define WS_DZ   307200
#define WS_PP   589824
#define WS_PART 589824
#define WS_RX   1114112
#define WS_SPS  1155072
#define WS_SPM  1175552
#define WS_SPA  1196032

// LDS-staged pool partials: grid (64 b-groups of 4, 16 item-chunks).
// Stage 256-item emb sub-tiles coalesced into LDS (17-float padded rows:
// stride-17 reads = 2 lanes/bank = conflict-free), then u-conditional adds for
// 4 batch rows per tile. Fixes round-6/9 pool's lane-stride-64B gather that
// serialized the TA coalescer (~200 GB/s, VALUBusy 3.6%).
__global__ __launch_bounds__(256) void pool_part(const int* __restrict__ u,
    const float* __restrict__ emb, float* __restrict__ pp) {
  __shared__ float se[256 * 17];  // 17.4 KB
  int g = blockIdx.x, c = blockIdx.y, t = threadIdx.x;
  int b0 = g * PB;
  float acc[PB][16];
  float cnt[PB];
  #pragma unroll
  for (int r = 0; r < PB; ++r) {
    cnt[r] = 0.f;
    #pragma unroll
    for (int e = 0; e < 16; ++e) acc[r][e] = 0.f;
  }
  int base0 = c * PCHUNK;
  const float4* emb4 = (const float4*)emb;
  #pragma unroll 1
  for (int st = 0; st < 13; ++st) {
    int base = base0 + st * 256;
    int tile = PCHUNK - st * 256; if (tile > 256) tile = 256;  // 256 or 53
    int nf4 = tile * 4;
    __syncthreads();
    for (int v = t; v < nf4; v += 256) {
      float4 f = emb4[(size_t)base * 4 + v];  // coalesced: consecutive 16B
      int item = v >> 2, p = (v & 3) * 4;
      se[item * 17 + p + 0] = f.x;
      se[item * 17 + p + 1] = f.y;
      se[item * 17 + p + 2] = f.z;
      se[item * 17 + p + 3] = f.w;
    }
    __syncthreads();
    if (t < tile) {
      int n = base + t;
      float ev[16];
      #pragma unroll
      for (int e = 0; e < 16; ++e) ev[e] = se[t * 17 + e];
      #pragma unroll
      for (int r = 0; r < PB; ++r) {
        if (u[(size_t)(b0 + r) * NITEMS + n]) {  // coalesced per r
          #pragma unroll
          for (int e = 0; e < 16; ++e) acc[r][e] += ev[e];
          cnt[r] += 1.f;
        }
      }
    }
  }
  #pragma unroll
  for (int off = 32; off > 0; off >>= 1) {
    #pragma unroll
    for (int r = 0; r < PB; ++r) {
      #pragma unroll
      for (int e = 0; e < 16; ++e) acc[r][e] += __shfl_down(acc[r][e], off);
      cnt[r] += __shfl_down(cnt[r], off);
    }
  }
  int lane = t & 63, wv = t >> 6;
  if (lane == 0) {
    #pragma unroll
    for (int r = 0; r < PB; ++r) {
      float* dst = pp + ((size_t)((b0 + r) * 16 + c) * 4 + wv) * 17;
      #pragma unroll
      for (int e = 0; e < 16; ++e) dst[e] = acc[r][e];
      dst[16] = cnt[r];
    }
  }
}

// Sum 64 wave-partials per b; build x = [slate(160)|user(16)|resp(1024)],
// dz[64:1104] = [user|resp].
__global__ __launch_bounds__(256) void build_x(const float* __restrict__ pp,
    const int* __restrict__ slate, const float* __restrict__ resp,
    const float* __restrict__ emb, float* __restrict__ x, float* __restrict__ dz) {
  __shared__ float fin[17];
  int b = blockIdx.x, t = threadIdx.x;
  if (t < 17) {
    float a = 0.f;
    const float* p = pp + (size_t)b * 64 * 17 + t;
    #pragma unroll
    for (int w = 0; w < 64; ++w) a += p[w * 17];
    fin[t] = a;
  }
  __syncthreads();
  float inv = 1.0f / fin[16];
  if (t < 16) {
    float uv = fin[t] * inv;
    x[b * 1200 + 160 + t] = uv;
    dz[b * 1104 + 64 + t] = uv;
  }
  if (t >= 32 && t < 192) {
    int i = t - 32;
    int k = i >> 4, e = i & 15;
    int it = slate[b * 10 + k];
    x[b * 1200 + i] = emb[(size_t)it * 16 + e];
  }
  for (int i = t; i < 1024; i += 256) {
    float r = resp[b * 1024 + i];
    x[b * 1200 + 176 + i] = r;
    dz[b * 1104 + 80 + i] = r;
  }
}

// Split-K partial GEMM: P[z][M,N] = A[M,ks:ke] @ B[N,ks:ke]^T (round-6 proven)
__global__ __launch_bounds__(256) void gemm64(const float* __restrict__ A,
    const float* __restrict__ B, float* __restrict__ P, int M, int N, int K, int kChunk) {
  __shared__ float As[16][68];
  __shared__ float Bs[16][68];
  int tid = threadIdx.x;
  int m0 = blockIdx.y * 64, n0 = blockIdx.x * 64;
  int ks = blockIdx.z * kChunk;
  int ke = ks + kChunk; if (ke > K) ke = K;
  int sr = tid >> 2, sc = (tid & 3) * 4;
  int tx = tid & 15, ty = tid >> 4;
  float acc[4][4];
  #pragma unroll
  for (int i = 0; i < 4; ++i)
    #pragma unroll
    for (int j = 0; j < 4; ++j) acc[i][j] = 0.f;
  for (int k0 = ks; k0 < ke; k0 += 16) {
    float4 av = make_float4(0.f, 0.f, 0.f, 0.f);
    float4 bv = make_float4(0.f, 0.f, 0.f, 0.f);
    if (k0 + sc < ke)
      av = *(const float4*)(A + (size_t)(m0 + sr) * K + k0 + sc);
    if (k0 + sc < ke && n0 + sr < N)
      bv = *(const float4*)(B + (size_t)(n0 + sr) * K + k0 + sc);
    __syncthreads();
    As[sc][sr] = av.x; As[sc + 1][sr] = av.y; As[sc + 2][sr] = av.z; As[sc + 3][sr] = av.w;
    Bs[sc][sr] = bv.x; Bs[sc + 1][sr] = bv.y; Bs[sc + 2][sr] = bv.z; Bs[sc + 3][sr] = bv.w;
    __syncthreads();
    #pragma unroll
    for (int kk = 0; kk < 16; ++kk) {
      float4 a4 = *(const float4*)&As[kk][4 * ty];
      float4 b4 = *(const float4*)&Bs[kk][4 * tx];
      float a[4] = {a4.x, a4.y, a4.z, a4.w};
      float b[4] = {b4.x, b4.y, b4.z, b4.w};
      #pragma unroll
      for (int i = 0; i < 4; ++i)
        #pragma unroll
        for (int j = 0; j < 4; ++j) acc[i][j] = fmaf(a[i], b[j], acc[i][j]);
    }
  }
  float* Pz = P + (size_t)blockIdx.z * M * N;
  #pragma unroll
  for (int i = 0; i < 4; ++i) {
    int m = m0 + 4 * ty + i, n = n0 + 4 * tx;
    if (n < N)
      *(float4*)(Pz + (size_t)m * N + n) = make_float4(acc[i][0], acc[i][1], acc[i][2], acc[i][3]);
  }
}

// h = relu(sum_s part[s] + b_enc); z_mean/z_log_var -> out; z -> dz[0:64]
__global__ __launch_bounds__(128) void mulv_z_kernel(const float* __restrict__ part,
    const float* __restrict__ benc,
    const float* __restrict__ Wmu, const float* __restrict__ bmu,
    const float* __restrict__ Wlv, const float* __restrict__ blv,
    const float* __restrict__ eps, float* __restrict__ out, float* __restrict__ dz) {
  __shared__ __align__(16) float hs[512];
  __shared__ float zms[64], zlvs[64];
  int b = blockIdx.x, t = threadIdx.x;
  for (int i = t; i < 512; i += 128) {
    float a = benc[i];
    #pragma unroll
    for (int s = 0; s < 4; ++s) a += part[(size_t)s * 131072 + b * 512 + i];
    hs[i] = fmaxf(a, 0.f);
  }
  __syncthreads();
  const float* Wr = (t < 64) ? (Wmu + (size_t)t * 512) : (Wlv + (size_t)(t - 64) * 512);
  float bias = (t < 64) ? bmu[t] : blv[t - 64];
  const float4* w4 = (const float4*)Wr;
  const float4* h4 = (const float4*)hs;
  float a0 = 0.f, a1 = 0.f, a2 = 0.f, a3 = 0.f;
  #pragma unroll 4
  for (int i = 0; i < 128; ++i) {
    float4 w = w4[i], hv = h4[i];
    a0 = fmaf(w.x, hv.x, a0); a1 = fmaf(w.y, hv.y, a1);
    a2 = fmaf(w.z, hv.z, a2); a3 = fmaf(w.w, hv.w, a3);
  }
  float acc = (a0 + a1) + (a2 + a3) + bias;
  if (t < 64) { out[OUT_ZM + b * 64 + t] = acc; zms[t] = acc; }
  else        { out[OUT_ZLV + b * 64 + (t - 64)] = acc; zlvs[t - 64] = acc; }
  __syncthreads();
  if (t < 64) {
    float zv = fmaf(eps[b * 64 + t], __builtin_amdgcn_exp2f(0.7213475204444817f * zlvs[t]), zms[t]);
    dz[b * 1104 + t] = zv;
  }
}

// d2 split-K GEMM with reduce-on-load A (round-6 config): grid (3,4,8), kChunk=64.
__global__ __launch_bounds__(256) void gemm_d2(const float* __restrict__ part,
    const float* __restrict__ bd1, const float* __restrict__ W, float* __restrict__ p2) {
  __shared__ float As[16][68];
  __shared__ float Bs[16][68];
  const int N = 160;
  int tid = threadIdx.x;
  int m0 = blockIdx.y * 64, n0 = blockIdx.x * 64;
  int ks = blockIdx.z * 64, ke = ks + 64;
  int sr = tid >> 2, sc = (tid & 3) * 4;
  int tx = tid & 15, ty = tid >> 4;
  float acc[4][4];
  #pragma unroll
  for (int i = 0; i < 4; ++i)
    #pragma unroll
    for (int j = 0; j < 4; ++j) acc[i][j] = 0.f;
  for (int k0 = ks; k0 < ke; k0 += 16) {
    int col = k0 + sc;
    const float* p = part + (size_t)(m0 + sr) * 512 + col;
    float4 a0 = *(const float4*)(p);
    float4 a1 = *(const float4*)(p + 131072);
    float4 a2 = *(const float4*)(p + 262144);
    float4 a3 = *(const float4*)(p + 393216);
    float4 bb = *(const float4*)(bd1 + col);
    float4 av;
    av.x = fmaxf(a0.x + a1.x + a2.x + a3.x + bb.x, 0.f);
    av.y = fmaxf(a0.y + a1.y + a2.y + a3.y + bb.y, 0.f);
    av.z = fmaxf(a0.z + a1.z + a2.z + a3.z + bb.z, 0.f);
    av.w = fmaxf(a0.w + a1.w + a2.w + a3.w + bb.w, 0.f);
    float4 bv = make_float4(0.f, 0.f, 0.f, 0.f);
    if (n0 + sr < N)
      bv = *(const float4*)(W + (size_t)(n0 + sr) * 512 + col);
    __syncthreads();
    As[sc][sr] = av.x; As[sc + 1][sr] = av.y; As[sc + 2][sr] = av.z; As[sc + 3][sr] = av.w;
    Bs[sc][sr] = bv.x; Bs[sc + 1][sr] = bv.y; Bs[sc + 2][sr] = bv.z; Bs[sc + 3][sr] = bv.w;
    __syncthreads();
    #pragma unroll
    for (int kk = 0; kk < 16; ++kk) {
      float4 a4 = *(const float4*)&As[kk][4 * ty];
      float4 b4 = *(const float4*)&Bs[kk][4 * tx];
      float a[4] = {a4.x, a4.y, a4.z, a4.w};
      float b[4] = {b4.x, b4.y, b4.z, b4.w};
      #pragma unroll
      for (int i = 0; i < 4; ++i)
        #pragma unroll
        for (int j = 0; j < 4; ++j) acc[i][j] = fmaf(a[i], b[j], acc[i][j]);
    }
  }
  float* Pz = p2 + (size_t)blockIdx.z * 40960;
  #pragma unroll
  for (int i = 0; i < 4; ++i) {
    int m = m0 + 4 * ty + i, n = n0 + 4 * tx;
    if (n < N)
      *(float4*)(Pz + (size_t)m * 160 + n) = make_float4(acc[i][0], acc[i][1], acc[i][2], acc[i][3]);
  }
}

// Per (b, chunk): fixed-shift softmax partials (round-6 measured: 118 us).
// Preamble finishes d2: rxs = relu(sum_z p2 + b_d2) * LOG2E; chunk-0 publishes rx.
// launch_bounds(256,2) load-bearing: round 4 showed min-waves=3 forces 620 MB spill.
__global__ __launch_bounds__(256, 2) void score_part(const float* __restrict__ p2,
    const float* __restrict__ bd2, const float* __restrict__ emb,
    float* __restrict__ rx, float* __restrict__ psg, float* __restrict__ pmg,
    int* __restrict__ pag) {
  __shared__ __align__(16) float rxs[160];
  __shared__ float wm[4][10], wsum[4][10];
  __shared__ int wa[4][10];
  int b = blockIdx.x, c = blockIdx.y, t = threadIdx.x;
  if (t < 160) {
    float a = bd2[t];
    #pragma unroll
    for (int z = 0; z < 8; ++z) a += p2[(size_t)z * 40960 + b * 160 + t];
    float v = fmaxf(a, 0.f) * LOG2E;
    rxs[t] = v;
    if (c == 0) rx[b * 160 + t] = v;
  }
  __syncthreads();
  float m[10], s[10];
  int am[10];
  #pragma unroll
  for (int k = 0; k < 10; ++k) { m[k] = -3.402823466e38f; s[k] = 0.f; am[k] = 0; }
  int nBase = c * CHUNK;
  const float4* ep = (const float4*)emb;
  #pragma unroll 1
  for (int j = 0; j < 12; ++j) {
    int n0 = nBase + j * 512 + t;
    float4 e[2][4];
    #pragma unroll
    for (int it = 0; it < 2; ++it) {
      const float4* p = ep + (size_t)(n0 + it * 256) * 4;
      e[it][0] = p[0]; e[it][1] = p[1]; e[it][2] = p[2]; e[it][3] = p[3];
    }
    #pragma unroll
    for (int k = 0; k < 10; ++k) {
      float4 r0 = *(const float4*)(rxs + k * 16);
      float4 r1 = *(const float4*)(rxs + k * 16 + 4);
      float4 r2 = *(const float4*)(rxs + k * 16 + 8);
      float4 r3 = *(const float4*)(rxs + k * 16 + 12);
      #pragma unroll
      for (int it = 0; it < 2; ++it) {
        float x0 = fmaf(e[it][0].x, r0.x, -SHIFT);
        float x1 = e[it][1].x * r1.x;
        float x2 = e[it][2].x * r2.x;
        float x3 = e[it][3].x * r3.x;
        x0 = fmaf(e[it][0].y, r0.y, x0);
        x1 = fmaf(e[it][1].y, r1.y, x1);
        x2 = fmaf(e[it][2].y, r2.y, x2);
        x3 = fmaf(e[it][3].y, r3.y, x3);
        x0 = fmaf(e[it][0].z, r0.z, x0);
        x1 = fmaf(e[it][1].z, r1.z, x1);
        x2 = fmaf(e[it][2].z, r2.z, x2);
        x3 = fmaf(e[it][3].z, r3.z, x3);
        x0 = fmaf(e[it][0].w, r0.w, x0);
        x1 = fmaf(e[it][1].w, r1.w, x1);
        x2 = fmaf(e[it][2].w, r2.w, x2);
        x3 = fmaf(e[it][3].w, r3.w, x3);
        float x = (x0 + x1) + (x2 + x3);
        s[k] += __builtin_amdgcn_exp2f(x);
        if (x > m[k]) { m[k] = x; am[k] = n0 + it * 256; }
      }
    }
  }
  // tail: 106 items
  if (t < CHUNK - 6144) {
    int n = nBase + 6144 + t;
    const float4* p = ep + (size_t)n * 4;
    float4 e0 = p[0], e1 = p[1], e2 = p[2], e3 = p[3];
    #pragma unroll
    for (int k = 0; k < 10; ++k) {
      const float4 r0 = *(const float4*)(rxs + k * 16);
      const float4 r1 = *(const float4*)(rxs + k * 16 + 4);
      const float4 r2 = *(const float4*)(rxs + k * 16 + 8);
      const float4 r3 = *(const float4*)(rxs + k * 16 + 12);
      float x0 = fmaf(e0.w, r0.w, fmaf(e0.z, r0.z, fmaf(e0.y, r0.y, fmaf(e0.x, r0.x, -SHIFT))));
      float x1 = fmaf(e1.w, r1.w, fmaf(e1.z, r1.z, fmaf(e1.y, r1.y, e1.x * r1.x)));
      float x2 = fmaf(e2.w, r2.w, fmaf(e2.z, r2.z, fmaf(e2.y, r2.y, e2.x * r2.x)));
      float x3 = fmaf(e3.w, r3.w, fmaf(e3.z, r3.z, fmaf(e3.y, r3.y, e3.x * r3.x)));
      float x = (x0 + x1) + (x2 + x3);
      s[k] += __builtin_amdgcn_exp2f(x);
      if (x > m[k]) { m[k] = x; am[k] = n; }
    }
  }
  #pragma unroll
  for (int off = 32; off > 0; off >>= 1) {
    #pragma unroll
    for (int k = 0; k < 10; ++k) {
      s[k] += __shfl_down(s[k], off);
      float om = __shfl_down(m[k], off);
      int oa = __shfl_down(am[k], off);
      bool take = (om > m[k]) || (om == m[k] && oa < am[k]);
      am[k] = take ? oa : am[k];
      m[k] = fmaxf(m[k], om);
    }
  }
  int lane = t & 63, wv = t >> 6;
  if (lane == 0) {
    #pragma unroll
    for (int k = 0; k < 10; ++k) { wm[wv][k] = m[k]; wsum[wv][k] = s[k]; wa[wv][k] = am[k]; }
  }
  __syncthreads();
  if (t < 10) {
    int k = t;
    float M = wm[0][k], S = wsum[0][k];
    int AM = wa[0][k];
    #pragma unroll
    for (int w = 1; w < 4; ++w) {
      float m2 = wm[w][k];
      int oa = wa[w][k];
      bool take = (m2 > M) || (m2 == M && oa < AM);
      AM = take ? oa : AM;
      M = fmaxf(M, m2);
      S += wsum[w][k];
    }
    int idx = (b * NCHUNK + c) * 10 + k;
    psg[idx] = S; pmg[idx] = M; pag[idx] = AM;
  }
}

// Combine chunk partials: S adds (shared fixed shift); argmax; slate prob.
__global__ __launch_bounds__(256) void score_final(const float* __restrict__ psg,
    const float* __restrict__ pmg, const int* __restrict__ pag,
    const float* __restrict__ rx, const float* __restrict__ emb,
    const int* __restrict__ slate, float* __restrict__ out) {
  int tid = blockIdx.x * 256 + threadIdx.x;
  if (tid >= BATCH * 10) return;
  int b = tid / 10, k = tid % 10;
  int base = b * NCHUNK * 10 + k;
  float S = 0.f, M = -3.402823466e38f;
  int AM = 2147483647;
  #pragma unroll
  for (int c = 0; c < NCHUNK; ++c) {
    S += psg[base + c * 10];
    float m2 = pmg[base + c * 10];
    int oa = pag[base + c * 10];
    bool take = (m2 > M) || (m2 == M && oa < AM);
    AM = take ? oa : AM;
    M = fmaxf(M, m2);
  }
  int it = slate[b * 10 + k];
  const float* er = emb + (size_t)it * 16;
  const float* rr = rx + b * 160 + k * 16;
  float xs = -SHIFT;
  #pragma unroll
  for (int e = 0; e < 16; ++e) xs = fmaf(rr[e], er[e], xs);
  out[OUT_RS + b * 10 + k] = (float)AM;
  out[OUT_RR + b * 10 + k] = __builtin_amdgcn_exp2f(xs) / S;
}

extern "C" void kernel_launch(void* const* d_in, const int* in_sizes, int n_in,
                              void* d_out, int out_size, void* d_ws, size_t ws_size,
                              hipStream_t stream) {
  const int* user_repr = (const int*)d_in[0];
  const int* slate = (const int*)d_in[1];
  const float* resp = (const float*)d_in[2];
  const float* eps = (const float*)d_in[3];
  const float* emb = (const float*)d_in[4];
  const float* W_enc = (const float*)d_in[5];
  const float* b_enc = (const float*)d_in[6];
  const float* W_mu = (const float*)d_in[7];
  const float* b_mu = (const float*)d_in[8];
  const float* W_lv = (const float*)d_in[9];
  const float* b_lv = (const float*)d_in[10];
  const float* W_d1 = (const float*)d_in[11];
  const float* b_d1 = (const float*)d_in[12];
  const float* W_d2 = (const float*)d_in[13];
  const float* b_d2 = (const float*)d_in[14];
  float* out = (float*)d_out;
  float* ws = (float*)d_ws;

  float* x    = ws + WS_X;
  float* dz   = ws + WS_DZ;
  float* pp   = ws + WS_PP;
  float* part = ws + WS_PART;
  float* p2   = ws + WS_P2;
  float* rx   = ws + WS_RX;
  float* sps  = ws + WS_SPS;
  float* spm  = ws + WS_SPM;
  int*   spa  = (int*)(ws + WS_SPA);

  pool_part<<<dim3(64, 16), 256, 0, stream>>>(user_repr, emb, pp);
  build_x<<<256, 256, 0, stream>>>(pp, slate, resp, emb, x, dz);
  gemm64<<<dim3(8, 4, 4), 256, 0, stream>>>(x, W_enc, part, 256, 512, 1200, 300);
  mulv_z_kernel<<<256, 128, 0, stream>>>(part, b_enc, W_mu, b_mu, W_lv, b_lv, eps, out, dz);
  gemm64<<<dim3(8, 4, 4), 256, 0, stream>>>(dz, W_d1, part, 256, 512, 1104, 276);
  gemm_d2<<<dim3(3, 4, 8), 256, 0, stream>>>(part, b_d1, W_d2, p2);
  score_part<<<dim3(256, 8), 256, 0, stream>>>(p2, b_d2, emb, rx, sps, spm, spa);
  score_final<<<10, 256, 0, stream>>>(sps, spm, spa, rx, emb, slate, out);
}

// Round 11
// 341.009 us; speedup vs baseline: 1.4360x; 1.0696x over previous
//
#include <hip/hip_runtime.h>

// Problem constants
#define NITEMS 50000
#define EMBD   16
#define NSLATE 10
#define HIDD   512
#define LATD   64
#define RESPD  1024
#define BATCH  256
#define NCHUNK 8
#define CHUNK  6250   // score: NITEMS/8
#define PCHUNK 3125   // pool: NITEMS/16
#define LOG2E  1.44269504088896340736f
#define SHIFT  64.0f  // fixed log2-domain shift: s = sum exp2(x*log2e - 64)

typedef float v2f __attribute__((ext_vector_type(2)));
#define LO2(f) ((v2f){(f).x, (f).y})
#define HI2(f) ((v2f){(f).z, (f).w})

// d_out layout (float): z_mean | z_log_var | recon_slate | recon_resp
#define OUT_ZM 0
#define OUT_ZLV 16384
#define OUT_RS 32768
#define OUT_RR 35328

// ws layout (floats), time-overlays (stream-ordered), round-6 proven footprint:
//   [0 .. 307200)        x (build -> enc)     OVERLAY p2[8*40960] (d2 -> score)
//   [307200 .. 589824)   dz (build/mulv -> d1)
//   [589824 .. 868352)   pp (pool partials, pool -> build_x)
//   [589824 .. 1114112)  OVERLAY part[4*131072] (enc->mulv, d1->d2)
//   [1114112 .. 1155072) rx[40960]
//   [1155072 .. 1216512) sps/spm/spa
#define WS_X    0
#define WS_P2   0
#define WS_DZ   307200
#define WS_PP   589824
#define WS_PART 589824
#define WS_RX   1114112
#define WS_SPS  1155072
#define WS_SPM  1175552
#define WS_SPA  1196032

// Cooperative-lane pool: grid (256 b, 16 c). 4 lanes per item (p = t&3 owns
// dims [4p..4p+4)); a wave's 64 lanes cover 16 consecutive items -> emb loads
// are one CONTIGUOUS 1KB per wave-instruction (fixes the 64-line gather that
// serialized the TA in rounds 5/6/9; round-10 LDS staging was also worse).
// xor-shuffle reduce over offsets 4..32 keeps p invariant; 4 lanes/wave write
// the 17-float partial. No LDS, no barriers.
__global__ __launch_bounds__(256) void pool_part(const int* __restrict__ u,
    const float* __restrict__ emb, float* __restrict__ pp) {
  int b = blockIdx.x, c = blockIdx.y, t = threadIdx.x;
  int p = t & 3;
  int nBase = c * PCHUNK, nEnd = nBase + PCHUNK;
  const int* ub = u + (size_t)b * NITEMS;
  const float4* e4 = (const float4*)emb;
  float4 acc = make_float4(0.f, 0.f, 0.f, 0.f);
  float cnt = 0.f;
  for (int n = nBase + (t >> 2); n < nEnd; n += 64) {
    int uv = ub[n];
    float4 e = e4[(size_t)n * 4 + p];
    if (uv) {
      acc.x += e.x; acc.y += e.y; acc.z += e.z; acc.w += e.w;
      cnt += (p == 0) ? 1.f : 0.f;
    }
  }
  #pragma unroll
  for (int off = 4; off < 64; off <<= 1) {
    acc.x += __shfl_xor(acc.x, off);
    acc.y += __shfl_xor(acc.y, off);
    acc.z += __shfl_xor(acc.z, off);
    acc.w += __shfl_xor(acc.w, off);
    cnt   += __shfl_xor(cnt, off);
  }
  int lane = t & 63, wv = t >> 6;
  if (lane < 4) {
    float* dst = pp + ((size_t)(b * 16 + c) * 4 + wv) * 17;
    dst[lane * 4 + 0] = acc.x;
    dst[lane * 4 + 1] = acc.y;
    dst[lane * 4 + 2] = acc.z;
    dst[lane * 4 + 3] = acc.w;
    if (lane == 0) dst[16] = cnt;
  }
}

// Sum 64 wave-partials per b; build x = [slate(160)|user(16)|resp(1024)],
// dz[64:1104] = [user|resp].
__global__ __launch_bounds__(256) void build_x(const float* __restrict__ pp,
    const int* __restrict__ slate, const float* __restrict__ resp,
    const float* __restrict__ emb, float* __restrict__ x, float* __restrict__ dz) {
  __shared__ float fin[17];
  int b = blockIdx.x, t = threadIdx.x;
  if (t < 17) {
    float a = 0.f;
    const float* p = pp + (size_t)b * 64 * 17 + t;
    #pragma unroll
    for (int w = 0; w < 64; ++w) a += p[w * 17];
    fin[t] = a;
  }
  __syncthreads();
  float inv = 1.0f / fin[16];
  if (t < 16) {
    float uv = fin[t] * inv;
    x[b * 1200 + 160 + t] = uv;
    dz[b * 1104 + 64 + t] = uv;
  }
  if (t >= 32 && t < 192) {
    int i = t - 32;
    int k = i >> 4, e = i & 15;
    int it = slate[b * 10 + k];
    x[b * 1200 + i] = emb[(size_t)it * 16 + e];
  }
  for (int i = t; i < 1024; i += 256) {
    float r = resp[b * 1024 + i];
    x[b * 1200 + 176 + i] = r;
    dz[b * 1104 + 80 + i] = r;
  }
}

// Split-K partial GEMM: P[z][M,N] = A[M,ks:ke] @ B[N,ks:ke]^T (round-6 proven)
__global__ __launch_bounds__(256) void gemm64(const float* __restrict__ A,
    const float* __restrict__ B, float* __restrict__ P, int M, int N, int K, int kChunk) {
  __shared__ float As[16][68];
  __shared__ float Bs[16][68];
  int tid = threadIdx.x;
  int m0 = blockIdx.y * 64, n0 = blockIdx.x * 64;
  int ks = blockIdx.z * kChunk;
  int ke = ks + kChunk; if (ke > K) ke = K;
  int sr = tid >> 2, sc = (tid & 3) * 4;
  int tx = tid & 15, ty = tid >> 4;
  float acc[4][4];
  #pragma unroll
  for (int i = 0; i < 4; ++i)
    #pragma unroll
    for (int j = 0; j < 4; ++j) acc[i][j] = 0.f;
  for (int k0 = ks; k0 < ke; k0 += 16) {
    float4 av = make_float4(0.f, 0.f, 0.f, 0.f);
    float4 bv = make_float4(0.f, 0.f, 0.f, 0.f);
    if (k0 + sc < ke)
      av = *(const float4*)(A + (size_t)(m0 + sr) * K + k0 + sc);
    if (k0 + sc < ke && n0 + sr < N)
      bv = *(const float4*)(B + (size_t)(n0 + sr) * K + k0 + sc);
    __syncthreads();
    As[sc][sr] = av.x; As[sc + 1][sr] = av.y; As[sc + 2][sr] = av.z; As[sc + 3][sr] = av.w;
    Bs[sc][sr] = bv.x; Bs[sc + 1][sr] = bv.y; Bs[sc + 2][sr] = bv.z; Bs[sc + 3][sr] = bv.w;
    __syncthreads();
    #pragma unroll
    for (int kk = 0; kk < 16; ++kk) {
      float4 a4 = *(const float4*)&As[kk][4 * ty];
      float4 b4 = *(const float4*)&Bs[kk][4 * tx];
      float a[4] = {a4.x, a4.y, a4.z, a4.w};
      float b[4] = {b4.x, b4.y, b4.z, b4.w};
      #pragma unroll
      for (int i = 0; i < 4; ++i)
        #pragma unroll
        for (int j = 0; j < 4; ++j) acc[i][j] = fmaf(a[i], b[j], acc[i][j]);
    }
  }
  float* Pz = P + (size_t)blockIdx.z * M * N;
  #pragma unroll
  for (int i = 0; i < 4; ++i) {
    int m = m0 + 4 * ty + i, n = n0 + 4 * tx;
    if (n < N)
      *(float4*)(Pz + (size_t)m * N + n) = make_float4(acc[i][0], acc[i][1], acc[i][2], acc[i][3]);
  }
}

// h = relu(sum_s part[s] + b_enc); z_mean/z_log_var -> out; z -> dz[0:64]
__global__ __launch_bounds__(128) void mulv_z_kernel(const float* __restrict__ part,
    const float* __restrict__ benc,
    const float* __restrict__ Wmu, const float* __restrict__ bmu,
    const float* __restrict__ Wlv, const float* __restrict__ blv,
    const float* __restrict__ eps, float* __restrict__ out, float* __restrict__ dz) {
  __shared__ __align__(16) float hs[512];
  __shared__ float zms[64], zlvs[64];
  int b = blockIdx.x, t = threadIdx.x;
  for (int i = t; i < 512; i += 128) {
    float a = benc[i];
    #pragma unroll
    for (int s = 0; s < 4; ++s) a += part[(size_t)s * 131072 + b * 512 + i];
    hs[i] = fmaxf(a, 0.f);
  }
  __syncthreads();
  const float* Wr = (t < 64) ? (Wmu + (size_t)t * 512) : (Wlv + (size_t)(t - 64) * 512);
  float bias = (t < 64) ? bmu[t] : blv[t - 64];
  const float4* w4 = (const float4*)Wr;
  const float4* h4 = (const float4*)hs;
  float a0 = 0.f, a1 = 0.f, a2 = 0.f, a3 = 0.f;
  #pragma unroll 4
  for (int i = 0; i < 128; ++i) {
    float4 w = w4[i], hv = h4[i];
    a0 = fmaf(w.x, hv.x, a0); a1 = fmaf(w.y, hv.y, a1);
    a2 = fmaf(w.z, hv.z, a2); a3 = fmaf(w.w, hv.w, a3);
  }
  float acc = (a0 + a1) + (a2 + a3) + bias;
  if (t < 64) { out[OUT_ZM + b * 64 + t] = acc; zms[t] = acc; }
  else        { out[OUT_ZLV + b * 64 + (t - 64)] = acc; zlvs[t - 64] = acc; }
  __syncthreads();
  if (t < 64) {
    float zv = fmaf(eps[b * 64 + t], __builtin_amdgcn_exp2f(0.7213475204444817f * zlvs[t]), zms[t]);
    dz[b * 1104 + t] = zv;
  }
}

// d2 split-K GEMM with reduce-on-load A (round-6 config): grid (3,4,8), kChunk=64.
__global__ __launch_bounds__(256) void gemm_d2(const float* __restrict__ part,
    const float* __restrict__ bd1, const float* __restrict__ W, float* __restrict__ p2) {
  __shared__ float As[16][68];
  __shared__ float Bs[16][68];
  const int N = 160;
  int tid = threadIdx.x;
  int m0 = blockIdx.y * 64, n0 = blockIdx.x * 64;
  int ks = blockIdx.z * 64, ke = ks + 64;
  int sr = tid >> 2, sc = (tid & 3) * 4;
  int tx = tid & 15, ty = tid >> 4;
  float acc[4][4];
  #pragma unroll
  for (int i = 0; i < 4; ++i)
    #pragma unroll
    for (int j = 0; j < 4; ++j) acc[i][j] = 0.f;
  for (int k0 = ks; k0 < ke; k0 += 16) {
    int col = k0 + sc;
    const float* p = part + (size_t)(m0 + sr) * 512 + col;
    float4 a0 = *(const float4*)(p);
    float4 a1 = *(const float4*)(p + 131072);
    float4 a2 = *(const float4*)(p + 262144);
    float4 a3 = *(const float4*)(p + 393216);
    float4 bb = *(const float4*)(bd1 + col);
    float4 av;
    av.x = fmaxf(a0.x + a1.x + a2.x + a3.x + bb.x, 0.f);
    av.y = fmaxf(a0.y + a1.y + a2.y + a3.y + bb.y, 0.f);
    av.z = fmaxf(a0.z + a1.z + a2.z + a3.z + bb.z, 0.f);
    av.w = fmaxf(a0.w + a1.w + a2.w + a3.w + bb.w, 0.f);
    float4 bv = make_float4(0.f, 0.f, 0.f, 0.f);
    if (n0 + sr < N)
      bv = *(const float4*)(W + (size_t)(n0 + sr) * 512 + col);
    __syncthreads();
    As[sc][sr] = av.x; As[sc + 1][sr] = av.y; As[sc + 2][sr] = av.z; As[sc + 3][sr] = av.w;
    Bs[sc][sr] = bv.x; Bs[sc + 1][sr] = bv.y; Bs[sc + 2][sr] = bv.z; Bs[sc + 3][sr] = bv.w;
    __syncthreads();
    #pragma unroll
    for (int kk = 0; kk < 16; ++kk) {
      float4 a4 = *(const float4*)&As[kk][4 * ty];
      float4 b4 = *(const float4*)&Bs[kk][4 * tx];
      float a[4] = {a4.x, a4.y, a4.z, a4.w};
      float b[4] = {b4.x, b4.y, b4.z, b4.w};
      #pragma unroll
      for (int i = 0; i < 4; ++i)
        #pragma unroll
        for (int j = 0; j < 4; ++j) acc[i][j] = fmaf(a[i], b[j], acc[i][j]);
    }
  }
  float* Pz = p2 + (size_t)blockIdx.z * 40960;
  #pragma unroll
  for (int i = 0; i < 4; ++i) {
    int m = m0 + 4 * ty + i, n = n0 + 4 * tx;
    if (n < N)
      *(float4*)(Pz + (size_t)m * 160 + n) = make_float4(acc[i][0], acc[i][1], acc[i][2], acc[i][3]);
  }
}

// Per (b, chunk): fixed-shift softmax partials, v_pk_fma_f32 dot products
// (float2 ext-vectors bitcast from the float4 registers: 8 pk_fma + 3 pk_add
// + 1 add vs 19 scalar ops). Structure otherwise = round-6/10 measured config.
// Preamble finishes d2: rxs = relu(sum_z p2 + b_d2) * LOG2E; chunk-0 publishes rx.
// launch_bounds(256,2) load-bearing: round 4 showed min-waves=3 forces 620 MB spill.
__global__ __launch_bounds__(256, 2) void score_part(const float* __restrict__ p2,
    const float* __restrict__ bd2, const float* __restrict__ emb,
    float* __restrict__ rx, float* __restrict__ psg, float* __restrict__ pmg,
    int* __restrict__ pag) {
  __shared__ __align__(16) float rxs[160];
  __shared__ float wm[4][10], wsum[4][10];
  __shared__ int wa[4][10];
  int b = blockIdx.x, c = blockIdx.y, t = threadIdx.x;
  if (t < 160) {
    float a = bd2[t];
    #pragma unroll
    for (int z = 0; z < 8; ++z) a += p2[(size_t)z * 40960 + b * 160 + t];
    float v = fmaxf(a, 0.f) * LOG2E;
    rxs[t] = v;
    if (c == 0) rx[b * 160 + t] = v;
  }
  __syncthreads();
  float m[10], s[10];
  int am[10];
  #pragma unroll
  for (int k = 0; k < 10; ++k) { m[k] = -3.402823466e38f; s[k] = 0.f; am[k] = 0; }
  int nBase = c * CHUNK;
  const float4* ep = (const float4*)emb;
  #pragma unroll 1
  for (int j = 0; j < 12; ++j) {
    int n0 = nBase + j * 512 + t;
    float4 e[2][4];
    #pragma unroll
    for (int it = 0; it < 2; ++it) {
      const float4* p = ep + (size_t)(n0 + it * 256) * 4;
      e[it][0] = p[0]; e[it][1] = p[1]; e[it][2] = p[2]; e[it][3] = p[3];
    }
    #pragma unroll
    for (int k = 0; k < 10; ++k) {
      float4 r0 = *(const float4*)(rxs + k * 16);
      float4 r1 = *(const float4*)(rxs + k * 16 + 4);
      float4 r2 = *(const float4*)(rxs + k * 16 + 8);
      float4 r3 = *(const float4*)(rxs + k * 16 + 12);
      v2f R0 = LO2(r0), R1 = HI2(r0), R2 = LO2(r1), R3 = HI2(r1);
      v2f R4 = LO2(r2), R5 = HI2(r2), R6 = LO2(r3), R7 = HI2(r3);
      #pragma unroll
      for (int it = 0; it < 2; ++it) {
        v2f a0 = __builtin_elementwise_fma(LO2(e[it][0]), R0, (v2f){-SHIFT, 0.f});
        v2f a1 = HI2(e[it][0]) * R1;
        v2f a2 = LO2(e[it][1]) * R2;
        v2f a3 = HI2(e[it][1]) * R3;
        a0 = __builtin_elementwise_fma(LO2(e[it][2]), R4, a0);
        a1 = __builtin_elementwise_fma(HI2(e[it][2]), R5, a1);
        a2 = __builtin_elementwise_fma(LO2(e[it][3]), R6, a2);
        a3 = __builtin_elementwise_fma(HI2(e[it][3]), R7, a3);
        v2f s01 = a0 + a1, s23 = a2 + a3;
        v2f ss = s01 + s23;
        float x = ss.x + ss.y;
        s[k] += __builtin_amdgcn_exp2f(x);
        if (x > m[k]) { m[k] = x; am[k] = n0 + it * 256; }
      }
    }
  }
  // tail: 106 items
  if (t < CHUNK - 6144) {
    int n = nBase + 6144 + t;
    const float4* p = ep + (size_t)n * 4;
    float4 e0 = p[0], e1 = p[1], e2 = p[2], e3 = p[3];
    #pragma unroll
    for (int k = 0; k < 10; ++k) {
      const float4 r0 = *(const float4*)(rxs + k * 16);
      const float4 r1 = *(const float4*)(rxs + k * 16 + 4);
      const float4 r2 = *(const float4*)(rxs + k * 16 + 8);
      const float4 r3 = *(const float4*)(rxs + k * 16 + 12);
      float x0 = fmaf(e0.w, r0.w, fmaf(e0.z, r0.z, fmaf(e0.y, r0.y, fmaf(e0.x, r0.x, -SHIFT))));
      float x1 = fmaf(e1.w, r1.w, fmaf(e1.z, r1.z, fmaf(e1.y, r1.y, e1.x * r1.x)));
      float x2 = fmaf(e2.w, r2.w, fmaf(e2.z, r2.z, fmaf(e2.y, r2.y, e2.x * r2.x)));
      float x3 = fmaf(e3.w, r3.w, fmaf(e3.z, r3.z, fmaf(e3.y, r3.y, e3.x * r3.x)));
      float x = (x0 + x1) + (x2 + x3);
      s[k] += __builtin_amdgcn_exp2f(x);
      if (x > m[k]) { m[k] = x; am[k] = n; }
    }
  }
  #pragma unroll
  for (int off = 32; off > 0; off >>= 1) {
    #pragma unroll
    for (int k = 0; k < 10; ++k) {
      s[k] += __shfl_down(s[k], off);
      float om = __shfl_down(m[k], off);
      int oa = __shfl_down(am[k], off);
      bool take = (om > m[k]) || (om == m[k] && oa < am[k]);
      am[k] = take ? oa : am[k];
      m[k] = fmaxf(m[k], om);
    }
  }
  int lane = t & 63, wv = t >> 6;
  if (lane == 0) {
    #pragma unroll
    for (int k = 0; k < 10; ++k) { wm[wv][k] = m[k]; wsum[wv][k] = s[k]; wa[wv][k] = am[k]; }
  }
  __syncthreads();
  if (t < 10) {
    int k = t;
    float M = wm[0][k], S = wsum[0][k];
    int AM = wa[0][k];
    #pragma unroll
    for (int w = 1; w < 4; ++w) {
      float m2 = wm[w][k];
      int oa = wa[w][k];
      bool take = (m2 > M) || (m2 == M && oa < AM);
      AM = take ? oa : AM;
      M = fmaxf(M, m2);
      S += wsum[w][k];
    }
    int idx = (b * NCHUNK + c) * 10 + k;
    psg[idx] = S; pmg[idx] = M; pag[idx] = AM;
  }
}

// Combine chunk partials: S adds (shared fixed shift); argmax; slate prob.
__global__ __launch_bounds__(256) void score_final(const float* __restrict__ psg,
    const float* __restrict__ pmg, const int* __restrict__ pag,
    const float* __restrict__ rx, const float* __restrict__ emb,
    const int* __restrict__ slate, float* __restrict__ out) {
  int tid = blockIdx.x * 256 + threadIdx.x;
  if (tid >= BATCH * 10) return;
  int b = tid / 10, k = tid % 10;
  int base = b * NCHUNK * 10 + k;
  float S = 0.f, M = -3.402823466e38f;
  int AM = 2147483647;
  #pragma unroll
  for (int c = 0; c < NCHUNK; ++c) {
    S += psg[base + c * 10];
    float m2 = pmg[base + c * 10];
    int oa = pag[base + c * 10];
    bool take = (m2 > M) || (m2 == M && oa < AM);
    AM = take ? oa : AM;
    M = fmaxf(M, m2);
  }
  int it = slate[b * 10 + k];
  const float* er = emb + (size_t)it * 16;
  const float* rr = rx + b * 160 + k * 16;
  float xs = -SHIFT;
  #pragma unroll
  for (int e = 0; e < 16; ++e) xs = fmaf(rr[e], er[e], xs);
  out[OUT_RS + b * 10 + k] = (float)AM;
  out[OUT_RR + b * 10 + k] = __builtin_amdgcn_exp2f(xs) / S;
}

extern "C" void kernel_launch(void* const* d_in, const int* in_sizes, int n_in,
                              void* d_out, int out_size, void* d_ws, size_t ws_size,
                              hipStream_t stream) {
  const int* user_repr = (const int*)d_in[0];
  const int* slate = (const int*)d_in[1];
  const float* resp = (const float*)d_in[2];
  const float* eps = (const float*)d_in[3];
  const float* emb = (const float*)d_in[4];
  const float* W_enc = (const float*)d_in[5];
  const float* b_enc = (const float*)d_in[6];
  const float* W_mu = (const float*)d_in[7];
  const float* b_mu = (const float*)d_in[8];
  const float* W_lv = (const float*)d_in[9];
  const float* b_lv = (const float*)d_in[10];
  const float* W_d1 = (const float*)d_in[11];
  const float* b_d1 = (const float*)d_in[12];
  const float* W_d2 = (const float*)d_in[13];
  const float* b_d2 = (const float*)d_in[14];
  float* out = (float*)d_out;
  float* ws = (float*)d_ws;

  float* x    = ws + WS_X;
  float* dz   = ws + WS_DZ;
  float* pp   = ws + WS_PP;
  float* part = ws + WS_PART;
  float* p2   = ws + WS_P2;
  float* rx   = ws + WS_RX;
  float* sps  = ws + WS_SPS;
  float* spm  = ws + WS_SPM;
  int*   spa  = (int*)(ws + WS_SPA);

  pool_part<<<dim3(256, 16), 256, 0, stream>>>(user_repr, emb, pp);
  build_x<<<256, 256, 0, stream>>>(pp, slate, resp, emb, x, dz);
  gemm64<<<dim3(8, 4, 4), 256, 0, stream>>>(x, W_enc, part, 256, 512, 1200, 300);
  mulv_z_kernel<<<256, 128, 0, stream>>>(part, b_enc, W_mu, b_mu, W_lv, b_lv, eps, out, dz);
  gemm64<<<dim3(8, 4, 4), 256, 0, stream>>>(dz, W_d1, part, 256, 512, 1104, 276);
  gemm_d2<<<dim3(3, 4, 8), 256, 0, stream>>>(part, b_d1, W_d2, p2);
  score_part<<<dim3(256, 8), 256, 0, stream>>>(p2, b_d2, emb, rx, sps, spm, spa);
  score_final<<<10, 256, 0, stream>>>(sps, spm, spa, rx, emb, slate, out);
}